// Round 1
// baseline (417.796 us; speedup 1.0000x reference)
//
#include <hip/hip_runtime.h>
#include <math.h>

#define NPTS 200
#define NCH  13
#define BLK  256

__global__ __launch_bounds__(BLK) void svd_align_kernel(
    const float* __restrict__ net_in,   // (B, 200, 13)
    const float* __restrict__ shift_p,  // (1,)
    const float* __restrict__ a_p,      // (1,)
    const float* __restrict__ b_p,      // (1,)
    float* __restrict__ out)            // (B, 200, 3)
{
    __shared__ float s_in[NPTS * NCH];    // 2600 floats
    __shared__ float s_out[NPTS * 3];     // 600 floats
    __shared__ float s_part[4][16];       // cross-wave partials
    __shared__ float s_Rt[12];            // R(9) + t(3)

    const int b   = blockIdx.x;
    const int tid = threadIdx.x;

    const float shift = shift_p[0];
    const float aa    = a_p[0];
    const float bb    = b_p[0];

    // ---- stage input batch into LDS (float4 coalesced; 2600*4B, 16B aligned) ----
    {
        const float4* src4 = (const float4*)(net_in + (size_t)b * (NPTS * NCH));
        float4* dst4 = (float4*)s_in;
        for (int i = tid; i < (NPTS * NCH) / 4; i += BLK) dst4[i] = src4[i];
    }
    __syncthreads();

    // ---- per-point compute + 16 partial sums ----
    float acc[16];
    #pragma unroll
    for (int k = 0; k < 16; ++k) acc[k] = 0.f;

    if (tid < NPTS) {
        const float* p = &s_in[tid * NCH];
        float w = aa * p[0] + bb;
        w = (w > 0.f ? w : 0.f) + 1e-8f;
        float v1x = fmaf(shift, p[7],  p[1]);
        float v1y = fmaf(shift, p[8],  p[2]);
        float v1z = fmaf(shift, p[9],  p[3]);
        float v2x = fmaf(shift, p[10], p[4]);
        float v2y = fmaf(shift, p[11], p[5]);
        float v2z = fmaf(shift, p[12], p[6]);
        acc[0] = w;
        acc[1] = w * v1x; acc[2] = w * v1y; acc[3] = w * v1z;
        acc[4] = w * v2x; acc[5] = w * v2y; acc[6] = w * v2z;
        // S[i][j] = w * v2_i * v1_j   (i indexes v2, j indexes v1)
        acc[7]  = acc[4] * v1x; acc[8]  = acc[4] * v1y; acc[9]  = acc[4] * v1z;
        acc[10] = acc[5] * v1x; acc[11] = acc[5] * v1y; acc[12] = acc[5] * v1z;
        acc[13] = acc[6] * v1x; acc[14] = acc[6] * v1y; acc[15] = acc[6] * v1z;
    }

    // ---- wave(64) shuffle reduction ----
    #pragma unroll
    for (int k = 0; k < 16; ++k) {
        float v = acc[k];
        #pragma unroll
        for (int off = 32; off > 0; off >>= 1) v += __shfl_down(v, off, 64);
        acc[k] = v;
    }
    const int wave = tid >> 6;
    const int lane = tid & 63;
    if (lane == 0) {
        #pragma unroll
        for (int k = 0; k < 16; ++k) s_part[wave][k] = acc[k];
    }
    __syncthreads();

    // ---- thread 0: solve the 3x3 Procrustes via Horn quaternion (fp64) ----
    if (tid == 0) {
        float f[16];
        #pragma unroll
        for (int k = 0; k < 16; ++k)
            f[k] = s_part[0][k] + s_part[1][k] + s_part[2][k] + s_part[3][k];

        double W = (double)f[0];
        double v1c[3] = { f[1] / W, f[2] / W, f[3] / W };
        double v2c[3] = { f[4] / W, f[5] / W, f[6] / W };

        // centered covariance: cov[i][j] = S[i][j] - W * v2c[i] * v1c[j]
        double S[3][3];
        #pragma unroll
        for (int i = 0; i < 3; ++i)
            #pragma unroll
            for (int j = 0; j < 3; ++j)
                S[i][j] = (double)f[7 + 3 * i + j] - W * v2c[i] * v1c[j];

        double Sxx = S[0][0], Sxy = S[0][1], Sxz = S[0][2];
        double Syx = S[1][0], Syy = S[1][1], Syz = S[1][2];
        double Szx = S[2][0], Szy = S[2][1], Szz = S[2][2];

        // Horn's 4x4 symmetric matrix (left = v2, right = v1; r_r = R r_l)
        double A[4][4];
        A[0][0] = Sxx + Syy + Szz;
        A[0][1] = Syz - Szy;  A[0][2] = Szx - Sxz;  A[0][3] = Sxy - Syx;
        A[1][1] = Sxx - Syy - Szz;
        A[1][2] = Sxy + Syx;  A[1][3] = Szx + Sxz;
        A[2][2] = -Sxx + Syy - Szz;
        A[2][3] = Syz + Szy;
        A[3][3] = -Sxx - Syy + Szz;
        A[1][0] = A[0][1]; A[2][0] = A[0][2]; A[3][0] = A[0][3];
        A[2][1] = A[1][2]; A[3][1] = A[1][3]; A[3][2] = A[2][3];

        double V[4][4] = {{1,0,0,0},{0,1,0,0},{0,0,1,0},{0,0,0,1}};

        const int prs[6][2] = {{0,1},{0,2},{0,3},{1,2},{1,3},{2,3}};
        for (int sweep = 0; sweep < 8; ++sweep) {
            for (int r = 0; r < 6; ++r) {
                const int p = prs[r][0], q = prs[r][1];
                double apq = A[p][q];
                if (apq == 0.0) continue;
                double tau = (A[q][q] - A[p][p]) / (2.0 * apq);
                double t = (tau >= 0.0 ? 1.0 : -1.0) /
                           (fabs(tau) + sqrt(1.0 + tau * tau));
                double c = 1.0 / sqrt(1.0 + t * t);
                double s = t * c;
                // A = J^T A
                #pragma unroll
                for (int k = 0; k < 4; ++k) {
                    double a1 = A[p][k], a2 = A[q][k];
                    A[p][k] = c * a1 - s * a2;
                    A[q][k] = s * a1 + c * a2;
                }
                // A = A J
                #pragma unroll
                for (int k = 0; k < 4; ++k) {
                    double a1 = A[k][p], a2 = A[k][q];
                    A[k][p] = c * a1 - s * a2;
                    A[k][q] = s * a1 + c * a2;
                }
                // V = V J
                #pragma unroll
                for (int k = 0; k < 4; ++k) {
                    double a1 = V[k][p], a2 = V[k][q];
                    V[k][p] = c * a1 - s * a2;
                    V[k][q] = s * a1 + c * a2;
                }
            }
        }

        int best = 0;
        #pragma unroll
        for (int i = 1; i < 4; ++i) if (A[i][i] > A[best][best]) best = i;
        double q0 = V[0][best], qx = V[1][best], qy = V[2][best], qz = V[3][best];

        double R00 = q0*q0 + qx*qx - qy*qy - qz*qz;
        double R01 = 2.0 * (qx*qy - q0*qz);
        double R02 = 2.0 * (qx*qz + q0*qy);
        double R10 = 2.0 * (qx*qy + q0*qz);
        double R11 = q0*q0 - qx*qx + qy*qy - qz*qz;
        double R12 = 2.0 * (qy*qz - q0*qx);
        double R20 = 2.0 * (qx*qz - q0*qy);
        double R21 = 2.0 * (qy*qz + q0*qx);
        double R22 = q0*q0 - qx*qx - qy*qy + qz*qz;

        double t0 = v1c[0] - (R00 * v2c[0] + R01 * v2c[1] + R02 * v2c[2]);
        double t1 = v1c[1] - (R10 * v2c[0] + R11 * v2c[1] + R12 * v2c[2]);
        double t2 = v1c[2] - (R20 * v2c[0] + R21 * v2c[1] + R22 * v2c[2]);

        s_Rt[0] = (float)R00; s_Rt[1] = (float)R01; s_Rt[2] = (float)R02;
        s_Rt[3] = (float)R10; s_Rt[4] = (float)R11; s_Rt[5] = (float)R12;
        s_Rt[6] = (float)R20; s_Rt[7] = (float)R21; s_Rt[8] = (float)R22;
        s_Rt[9] = (float)t0;  s_Rt[10] = (float)t1; s_Rt[11] = (float)t2;
    }
    __syncthreads();

    // ---- apply R,t to raw xyz2 ----
    if (tid < NPTS) {
        const float* p = &s_in[tid * NCH];
        float x = p[4], y = p[5], z = p[6];
        s_out[tid * 3 + 0] = s_Rt[0] * x + s_Rt[1] * y + s_Rt[2] * z + s_Rt[9];
        s_out[tid * 3 + 1] = s_Rt[3] * x + s_Rt[4] * y + s_Rt[5] * z + s_Rt[10];
        s_out[tid * 3 + 2] = s_Rt[6] * x + s_Rt[7] * y + s_Rt[8] * z + s_Rt[11];
    }
    __syncthreads();

    // ---- coalesced float4 store (600*4B per batch, 16B aligned) ----
    {
        float4* dst4 = (float4*)(out + (size_t)b * (NPTS * 3));
        const float4* src4 = (const float4*)s_out;
        for (int i = tid; i < (NPTS * 3) / 4; i += BLK) dst4[i] = src4[i];
    }
}

extern "C" void kernel_launch(void* const* d_in, const int* in_sizes, int n_in,
                              void* d_out, int out_size, void* d_ws, size_t ws_size,
                              hipStream_t stream) {
    const float* net_in  = (const float*)d_in[0];
    const float* shift_p = (const float*)d_in[1];
    const float* a_p     = (const float*)d_in[2];
    const float* b_p     = (const float*)d_in[3];
    float* out = (float*)d_out;

    const int B = in_sizes[0] / (NPTS * NCH);   // 8192
    svd_align_kernel<<<B, BLK, 0, stream>>>(net_in, shift_p, a_p, b_p, out);
}

// Round 2
// 193.231 us; speedup vs baseline: 2.1622x; 2.1622x over previous
//
#include <hip/hip_runtime.h>
#include <math.h>

#define NPTS 200
#define NCH  13
#define BLK  256

// ---------------------------------------------------------------------------
// Kernel 1: per-batch weighted reductions (16 sums) + compact xyz2 -> d_out
// ---------------------------------------------------------------------------
__global__ __launch_bounds__(BLK) void reduce_kernel(
    const float* __restrict__ net_in,   // (B, 200, 13)
    const float* __restrict__ shift_p,
    const float* __restrict__ a_p,
    const float* __restrict__ b_p,
    float* __restrict__ sums,           // (B, 16)
    float* __restrict__ out)            // (B, 200, 3)  <- raw xyz2 staged here
{
    __shared__ float s_in[NPTS * NCH];    // 2600 floats
    __shared__ float s_out[NPTS * 3];     // 600 floats
    __shared__ float s_part[4][16];

    const int b   = blockIdx.x;
    const int tid = threadIdx.x;

    const float shift = shift_p[0];
    const float aa    = a_p[0];
    const float bb    = b_p[0];

    // stage input batch into LDS (float4 coalesced; 2600 floats)
    {
        const float4* src4 = (const float4*)(net_in + (size_t)b * (NPTS * NCH));
        float4* dst4 = (float4*)s_in;
        for (int i = tid; i < (NPTS * NCH) / 4; i += BLK) dst4[i] = src4[i];
    }
    __syncthreads();

    float acc[16];
    #pragma unroll
    for (int k = 0; k < 16; ++k) acc[k] = 0.f;

    if (tid < NPTS) {
        const float* p = &s_in[tid * NCH];
        float w = aa * p[0] + bb;
        w = (w > 0.f ? w : 0.f) + 1e-8f;
        float v1x = fmaf(shift, p[7],  p[1]);
        float v1y = fmaf(shift, p[8],  p[2]);
        float v1z = fmaf(shift, p[9],  p[3]);
        float v2x = fmaf(shift, p[10], p[4]);
        float v2y = fmaf(shift, p[11], p[5]);
        float v2z = fmaf(shift, p[12], p[6]);
        acc[0] = w;
        acc[1] = w * v1x; acc[2] = w * v1y; acc[3] = w * v1z;
        acc[4] = w * v2x; acc[5] = w * v2y; acc[6] = w * v2z;
        acc[7]  = acc[4] * v1x; acc[8]  = acc[4] * v1y; acc[9]  = acc[4] * v1z;
        acc[10] = acc[5] * v1x; acc[11] = acc[5] * v1y; acc[12] = acc[5] * v1z;
        acc[13] = acc[6] * v1x; acc[14] = acc[6] * v1y; acc[15] = acc[6] * v1z;

        // compact raw xyz2 for the apply pass
        s_out[tid * 3 + 0] = p[4];
        s_out[tid * 3 + 1] = p[5];
        s_out[tid * 3 + 2] = p[6];
    }

    // wave(64) shuffle reduction of the 16 partials
    #pragma unroll
    for (int k = 0; k < 16; ++k) {
        float v = acc[k];
        #pragma unroll
        for (int off = 32; off > 0; off >>= 1) v += __shfl_down(v, off, 64);
        acc[k] = v;
    }
    const int wave = tid >> 6;
    const int lane = tid & 63;
    if (lane == 0) {
        #pragma unroll
        for (int k = 0; k < 16; ++k) s_part[wave][k] = acc[k];
    }
    __syncthreads();

    if (tid < 16)
        sums[(size_t)b * 16 + tid] =
            s_part[0][tid] + s_part[1][tid] + s_part[2][tid] + s_part[3][tid];

    // coalesced float4 store of compacted xyz2
    {
        float4* dst4 = (float4*)(out + (size_t)b * (NPTS * 3));
        const float4* src4 = (const float4*)s_out;
        for (int i = tid; i < (NPTS * 3) / 4; i += BLK) dst4[i] = src4[i];
    }
}

// ---------------------------------------------------------------------------
// Kernel 2: one thread per batch — fp64 Horn quaternion / 4x4 Jacobi solve
// ---------------------------------------------------------------------------
__global__ __launch_bounds__(BLK) void solve_kernel(
    const float* __restrict__ sums,   // (B, 16)
    float* __restrict__ Rt,           // (B, 12)
    int B)
{
    const int b = blockIdx.x * BLK + threadIdx.x;
    if (b >= B) return;

    float f[16];
    #pragma unroll
    for (int k = 0; k < 16; ++k) f[k] = sums[(size_t)b * 16 + k];

    double W = (double)f[0];
    double v1c[3] = { f[1] / W, f[2] / W, f[3] / W };
    double v2c[3] = { f[4] / W, f[5] / W, f[6] / W };

    double S[3][3];
    #pragma unroll
    for (int i = 0; i < 3; ++i)
        #pragma unroll
        for (int j = 0; j < 3; ++j)
            S[i][j] = (double)f[7 + 3 * i + j] - W * v2c[i] * v1c[j];

    double Sxx = S[0][0], Sxy = S[0][1], Sxz = S[0][2];
    double Syx = S[1][0], Syy = S[1][1], Syz = S[1][2];
    double Szx = S[2][0], Szy = S[2][1], Szz = S[2][2];

    double A[4][4];
    A[0][0] = Sxx + Syy + Szz;
    A[0][1] = Syz - Szy;  A[0][2] = Szx - Sxz;  A[0][3] = Sxy - Syx;
    A[1][1] = Sxx - Syy - Szz;
    A[1][2] = Sxy + Syx;  A[1][3] = Szx + Sxz;
    A[2][2] = -Sxx + Syy - Szz;
    A[2][3] = Syz + Szy;
    A[3][3] = -Sxx - Syy + Szz;
    A[1][0] = A[0][1]; A[2][0] = A[0][2]; A[3][0] = A[0][3];
    A[2][1] = A[1][2]; A[3][1] = A[1][3]; A[3][2] = A[2][3];

    double V[4][4] = {{1,0,0,0},{0,1,0,0},{0,0,1,0},{0,0,0,1}};

    const int prs[6][2] = {{0,1},{0,2},{0,3},{1,2},{1,3},{2,3}};
    for (int sweep = 0; sweep < 8; ++sweep) {
        #pragma unroll
        for (int r = 0; r < 6; ++r) {
            const int p = prs[r][0], q = prs[r][1];
            double apq = A[p][q];
            if (apq != 0.0) {
                double tau = (A[q][q] - A[p][p]) / (2.0 * apq);
                double t = (tau >= 0.0 ? 1.0 : -1.0) /
                           (fabs(tau) + sqrt(1.0 + tau * tau));
                double c = 1.0 / sqrt(1.0 + t * t);
                double s = t * c;
                #pragma unroll
                for (int k = 0; k < 4; ++k) {
                    double a1 = A[p][k], a2 = A[q][k];
                    A[p][k] = c * a1 - s * a2;
                    A[q][k] = s * a1 + c * a2;
                }
                #pragma unroll
                for (int k = 0; k < 4; ++k) {
                    double a1 = A[k][p], a2 = A[k][q];
                    A[k][p] = c * a1 - s * a2;
                    A[k][q] = s * a1 + c * a2;
                }
                #pragma unroll
                for (int k = 0; k < 4; ++k) {
                    double a1 = V[k][p], a2 = V[k][q];
                    V[k][p] = c * a1 - s * a2;
                    V[k][q] = s * a1 + c * a2;
                }
            }
        }
    }

    int best = 0;
    #pragma unroll
    for (int i = 1; i < 4; ++i) if (A[i][i] > A[best][best]) best = i;
    double q0 = V[0][best], qx = V[1][best], qy = V[2][best], qz = V[3][best];

    double R00 = q0*q0 + qx*qx - qy*qy - qz*qz;
    double R01 = 2.0 * (qx*qy - q0*qz);
    double R02 = 2.0 * (qx*qz + q0*qy);
    double R10 = 2.0 * (qx*qy + q0*qz);
    double R11 = q0*q0 - qx*qx + qy*qy - qz*qz;
    double R12 = 2.0 * (qy*qz - q0*qx);
    double R20 = 2.0 * (qx*qz - q0*qy);
    double R21 = 2.0 * (qy*qz + q0*qx);
    double R22 = q0*q0 - qx*qx - qy*qy + qz*qz;

    double t0 = v1c[0] - (R00 * v2c[0] + R01 * v2c[1] + R02 * v2c[2]);
    double t1 = v1c[1] - (R10 * v2c[0] + R11 * v2c[1] + R12 * v2c[2]);
    double t2 = v1c[2] - (R20 * v2c[0] + R21 * v2c[1] + R22 * v2c[2]);

    float* o = Rt + (size_t)b * 12;
    o[0] = (float)R00; o[1]  = (float)R01; o[2]  = (float)R02;
    o[3] = (float)R10; o[4]  = (float)R11; o[5]  = (float)R12;
    o[6] = (float)R20; o[7]  = (float)R21; o[8]  = (float)R22;
    o[9] = (float)t0;  o[10] = (float)t1;  o[11] = (float)t2;
}

// ---------------------------------------------------------------------------
// Kernel 3: apply R,t to the compacted xyz2 stored in d_out (in place)
// ---------------------------------------------------------------------------
__global__ __launch_bounds__(BLK) void apply_kernel(
    const float* __restrict__ Rt,   // (B, 12)
    float* __restrict__ out)        // (B, 200, 3) in: xyz2, out: aligned coords
{
    __shared__ float s_xyz[NPTS * 3];
    __shared__ float s_res[NPTS * 3];
    __shared__ float s_Rt[12];

    const int b   = blockIdx.x;
    const int tid = threadIdx.x;

    if (tid < 12) s_Rt[tid] = Rt[(size_t)b * 12 + tid];

    {
        const float4* src4 = (const float4*)(out + (size_t)b * (NPTS * 3));
        float4* dst4 = (float4*)s_xyz;
        for (int i = tid; i < (NPTS * 3) / 4; i += BLK) dst4[i] = src4[i];
    }
    __syncthreads();

    if (tid < NPTS) {
        float x = s_xyz[tid * 3 + 0];
        float y = s_xyz[tid * 3 + 1];
        float z = s_xyz[tid * 3 + 2];
        s_res[tid * 3 + 0] = s_Rt[0] * x + s_Rt[1] * y + s_Rt[2] * z + s_Rt[9];
        s_res[tid * 3 + 1] = s_Rt[3] * x + s_Rt[4] * y + s_Rt[5] * z + s_Rt[10];
        s_res[tid * 3 + 2] = s_Rt[6] * x + s_Rt[7] * y + s_Rt[8] * z + s_Rt[11];
    }
    __syncthreads();

    {
        float4* dst4 = (float4*)(out + (size_t)b * (NPTS * 3));
        const float4* src4 = (const float4*)s_res;
        for (int i = tid; i < (NPTS * 3) / 4; i += BLK) dst4[i] = src4[i];
    }
}

extern "C" void kernel_launch(void* const* d_in, const int* in_sizes, int n_in,
                              void* d_out, int out_size, void* d_ws, size_t ws_size,
                              hipStream_t stream) {
    const float* net_in  = (const float*)d_in[0];
    const float* shift_p = (const float*)d_in[1];
    const float* a_p     = (const float*)d_in[2];
    const float* b_p     = (const float*)d_in[3];
    float* out = (float*)d_out;

    const int B = in_sizes[0] / (NPTS * NCH);   // 8192

    float* sums = (float*)d_ws;                 // B * 16 floats
    float* Rt   = sums + (size_t)B * 16;        // B * 12 floats

    reduce_kernel<<<B, BLK, 0, stream>>>(net_in, shift_p, a_p, b_p, sums, out);
    solve_kernel<<<(B + BLK - 1) / BLK, BLK, 0, stream>>>(sums, Rt, B);
    apply_kernel<<<B, BLK, 0, stream>>>(Rt, out);
}

// Round 3
// 178.314 us; speedup vs baseline: 2.3430x; 1.0837x over previous
//
#include <hip/hip_runtime.h>
#include <math.h>

#define NPTS 200
#define NCH  13
#define BPB  4      // batches per reduce block
#define BLK  256

// ---------------------------------------------------------------------------
// Kernel 1: reduce — 4 batches/block, 1 wave/batch. 16 weighted sums per
// batch + compacted xyz2 written to d_out.
// ---------------------------------------------------------------------------
__global__ __launch_bounds__(BLK) void reduce_kernel(
    const float* __restrict__ net_in,   // (B, 200, 13)
    const float* __restrict__ shift_p,
    const float* __restrict__ a_p,
    const float* __restrict__ b_p,
    float* __restrict__ sums,           // (B, 16)
    float* __restrict__ out)            // (B, 200, 3) <- raw xyz2 staged here
{
    __shared__ float s_in[BPB * NPTS * NCH];     // 4*2600 = 10400 floats (41.6 KB)
    __shared__ float s_part[BPB][16][20];        // 16x16 transpose, pad 20 (5.1 KB)

    const int tid = threadIdx.x;
    const int w   = tid >> 6;        // wave = local batch
    const int l   = tid & 63;
    const int b0  = blockIdx.x * BPB;

    const float shift = shift_p[0];
    const float aa    = a_p[0];
    const float bb    = b_p[0];

    // ---- stage 4 batches, fully coalesced float4 ----
    {
        const float4* src4 = (const float4*)(net_in + (size_t)b0 * (NPTS * NCH));
        float4* dst4 = (float4*)s_in;
        for (int i = tid; i < BPB * NPTS * NCH / 4; i += BLK) dst4[i] = src4[i];
    }
    __syncthreads();

    // ---- per-lane serial accumulation over 3-4 points (all lanes active) ----
    float acc[16];
    #pragma unroll
    for (int k = 0; k < 16; ++k) acc[k] = 0.f;

    const float* base = s_in + w * (NPTS * NCH);
    #pragma unroll
    for (int j = 0; j < 4; ++j) {
        const int p = l + 64 * j;
        if (p < NPTS) {
            const float* q = base + p * NCH;      // stride 13 floats: conflict-free
            float wt = aa * q[0] + bb;
            wt = fmaxf(wt, 0.f) + 1e-8f;
            float v1x = fmaf(shift, q[7],  q[1]);
            float v1y = fmaf(shift, q[8],  q[2]);
            float v1z = fmaf(shift, q[9],  q[3]);
            float v2x = fmaf(shift, q[10], q[4]);
            float v2y = fmaf(shift, q[11], q[5]);
            float v2z = fmaf(shift, q[12], q[6]);
            float wv2x = wt * v2x, wv2y = wt * v2y, wv2z = wt * v2z;
            acc[0] += wt;
            acc[1] += wt * v1x; acc[2] += wt * v1y; acc[3] += wt * v1z;
            acc[4] += wv2x;     acc[5] += wv2y;     acc[6] += wv2z;
            acc[7]  += wv2x * v1x; acc[8]  += wv2x * v1y; acc[9]  += wv2x * v1z;
            acc[10] += wv2y * v1x; acc[11] += wv2y * v1y; acc[12] += wv2y * v1z;
            acc[13] += wv2z * v1x; acc[14] += wv2z * v1y; acc[15] += wv2z * v1z;
        }
    }

    // ---- 2 shuffle levels: 64 -> 16 lanes (32 DS insts) ----
    #pragma unroll
    for (int k = 0; k < 16; ++k) {
        acc[k] += __shfl_down(acc[k], 32, 64);
        acc[k] += __shfl_down(acc[k], 16, 64);
    }

    // ---- 16x16 LDS transpose: 4 b128 writes, then column sums ----
    if (l < 16) {
        float4* pp = (float4*)&s_part[w][l][0];
        pp[0] = make_float4(acc[0],  acc[1],  acc[2],  acc[3]);
        pp[1] = make_float4(acc[4],  acc[5],  acc[6],  acc[7]);
        pp[2] = make_float4(acc[8],  acc[9],  acc[10], acc[11]);
        pp[3] = make_float4(acc[12], acc[13], acc[14], acc[15]);
    }
    __syncthreads();

    if (l < 16) {
        float s = 0.f;
        #pragma unroll
        for (int r = 0; r < 16; ++r) s += s_part[w][r][l];   // banks distinct
        sums[(size_t)(b0 + w) * 16 + l] = s;
    }

    // ---- compacted xyz2 store: gather from s_in, coalesced float4 out ----
    for (int i = tid; i < BPB * NPTS * 3 / 4; i += BLK) {
        const int bb2 = i / 150;            // local batch
        const int q   = i - bb2 * 150;      // float4 index within batch
        const int f0  = q * 4;
        const float* bs = s_in + bb2 * (NPTS * NCH);
        float4 v;
        v.x = bs[((f0 + 0) / 3) * NCH + 4 + (f0 + 0) % 3];
        v.y = bs[((f0 + 1) / 3) * NCH + 4 + (f0 + 1) % 3];
        v.z = bs[((f0 + 2) / 3) * NCH + 4 + (f0 + 2) % 3];
        v.w = bs[((f0 + 3) / 3) * NCH + 4 + (f0 + 3) % 3];
        ((float4*)(out + (size_t)(b0 + bb2) * (NPTS * 3)))[q] = v;
    }
}

// ---------------------------------------------------------------------------
// Kernel 2: one thread per batch — fp32 Horn quaternion / 4x4 Jacobi
// ---------------------------------------------------------------------------
__global__ __launch_bounds__(64) void solve_kernel(
    const float* __restrict__ sums,   // (B, 16)
    float* __restrict__ Rt,           // (B, 12)
    int B)
{
    const int b = blockIdx.x * 64 + threadIdx.x;
    if (b >= B) return;

    float f[16];
    #pragma unroll
    for (int k = 0; k < 16; ++k) f[k] = sums[(size_t)b * 16 + k];

    const float W = f[0];
    const float invW = 1.0f / W;
    float v1c[3] = { f[1] * invW, f[2] * invW, f[3] * invW };
    float v2c[3] = { f[4] * invW, f[5] * invW, f[6] * invW };

    float S[3][3];
    #pragma unroll
    for (int i = 0; i < 3; ++i)
        #pragma unroll
        for (int j = 0; j < 3; ++j)
            S[i][j] = f[7 + 3 * i + j] - W * v2c[i] * v1c[j];

    const float Sxx = S[0][0], Sxy = S[0][1], Sxz = S[0][2];
    const float Syx = S[1][0], Syy = S[1][1], Syz = S[1][2];
    const float Szx = S[2][0], Szy = S[2][1], Szz = S[2][2];

    float A[4][4];
    A[0][0] = Sxx + Syy + Szz;
    A[0][1] = Syz - Szy;  A[0][2] = Szx - Sxz;  A[0][3] = Sxy - Syx;
    A[1][1] = Sxx - Syy - Szz;
    A[1][2] = Sxy + Syx;  A[1][3] = Szx + Sxz;
    A[2][2] = -Sxx + Syy - Szz;
    A[2][3] = Syz + Szy;
    A[3][3] = -Sxx - Syy + Szz;
    A[1][0] = A[0][1]; A[2][0] = A[0][2]; A[3][0] = A[0][3];
    A[2][1] = A[1][2]; A[3][1] = A[1][3]; A[3][2] = A[2][3];

    float V[4][4] = {{1,0,0,0},{0,1,0,0},{0,0,1,0},{0,0,0,1}};

    const int prs[6][2] = {{0,1},{0,2},{0,3},{1,2},{1,3},{2,3}};
    for (int sweep = 0; sweep < 6; ++sweep) {
        #pragma unroll
        for (int r = 0; r < 6; ++r) {
            const int p = prs[r][0], q = prs[r][1];
            float apq = A[p][q];
            if (apq != 0.0f) {
                float tau = (A[q][q] - A[p][p]) / (2.0f * apq);
                float t = copysignf(1.0f, tau) /
                          (fabsf(tau) + sqrtf(1.0f + tau * tau));
                float c = rsqrtf(1.0f + t * t);
                float s = t * c;
                #pragma unroll
                for (int k = 0; k < 4; ++k) {
                    float a1 = A[p][k], a2 = A[q][k];
                    A[p][k] = c * a1 - s * a2;
                    A[q][k] = s * a1 + c * a2;
                }
                #pragma unroll
                for (int k = 0; k < 4; ++k) {
                    float a1 = A[k][p], a2 = A[k][q];
                    A[k][p] = c * a1 - s * a2;
                    A[k][q] = s * a1 + c * a2;
                }
                #pragma unroll
                for (int k = 0; k < 4; ++k) {
                    float a1 = V[k][p], a2 = V[k][q];
                    V[k][p] = c * a1 - s * a2;
                    V[k][q] = s * a1 + c * a2;
                }
            }
        }
    }

    int best = 0;
    #pragma unroll
    for (int i = 1; i < 4; ++i) if (A[i][i] > A[best][best]) best = i;
    const float q0 = V[0][best], qx = V[1][best], qy = V[2][best], qz = V[3][best];

    const float R00 = q0*q0 + qx*qx - qy*qy - qz*qz;
    const float R01 = 2.0f * (qx*qy - q0*qz);
    const float R02 = 2.0f * (qx*qz + q0*qy);
    const float R10 = 2.0f * (qx*qy + q0*qz);
    const float R11 = q0*q0 - qx*qx + qy*qy - qz*qz;
    const float R12 = 2.0f * (qy*qz - q0*qx);
    const float R20 = 2.0f * (qx*qz - q0*qy);
    const float R21 = 2.0f * (qy*qz + q0*qx);
    const float R22 = q0*q0 - qx*qx - qy*qy + qz*qz;

    const float t0 = v1c[0] - (R00 * v2c[0] + R01 * v2c[1] + R02 * v2c[2]);
    const float t1 = v1c[1] - (R10 * v2c[0] + R11 * v2c[1] + R12 * v2c[2]);
    const float t2 = v1c[2] - (R20 * v2c[0] + R21 * v2c[1] + R22 * v2c[2]);

    float* o = Rt + (size_t)b * 12;
    o[0] = R00; o[1]  = R01; o[2]  = R02;
    o[3] = R10; o[4]  = R11; o[5]  = R12;
    o[6] = R20; o[7]  = R21; o[8]  = R22;
    o[9] = t0;  o[10] = t1;  o[11] = t2;
}

// ---------------------------------------------------------------------------
// Kernel 3: apply — 1 thread per 4 points (200 % 4 == 0 so no straddling),
// pure streaming, no LDS, no barriers. In-place on d_out.
// ---------------------------------------------------------------------------
__global__ __launch_bounds__(BLK) void apply_kernel(
    const float* __restrict__ Rt,   // (B, 12)
    float* __restrict__ out,        // (B, 200, 3) in: xyz2, out: result
    int B)
{
    const int g = blockIdx.x * BLK + threadIdx.x;   // 4-point group id
    if (g >= B * 50) return;
    const int b = g / 50;
    const int q = g - b * 50;

    const float* r = Rt + (size_t)b * 12;
    const float R00 = r[0], R01 = r[1], R02 = r[2];
    const float R10 = r[3], R11 = r[4], R12 = r[5];
    const float R20 = r[6], R21 = r[7], R22 = r[8];
    const float t0  = r[9], t1  = r[10], t2 = r[11];

    float4* p = (float4*)(out + (size_t)b * (NPTS * 3)) + q * 3;
    const float4 A0 = p[0], A1 = p[1], A2 = p[2];

    // unpack 4 points
    const float x0 = A0.x, y0 = A0.y, z0 = A0.z;
    const float x1 = A0.w, y1 = A1.x, z1 = A1.y;
    const float x2 = A1.z, y2 = A1.w, z2 = A2.x;
    const float x3 = A2.y, y3 = A2.z, z3 = A2.w;

    const float nx0 = R00*x0 + R01*y0 + R02*z0 + t0;
    const float ny0 = R10*x0 + R11*y0 + R12*z0 + t1;
    const float nz0 = R20*x0 + R21*y0 + R22*z0 + t2;
    const float nx1 = R00*x1 + R01*y1 + R02*z1 + t0;
    const float ny1 = R10*x1 + R11*y1 + R12*z1 + t1;
    const float nz1 = R20*x1 + R21*y1 + R22*z1 + t2;
    const float nx2 = R00*x2 + R01*y2 + R02*z2 + t0;
    const float ny2 = R10*x2 + R11*y2 + R12*z2 + t1;
    const float nz2 = R20*x2 + R21*y2 + R22*z2 + t2;
    const float nx3 = R00*x3 + R01*y3 + R02*z3 + t0;
    const float ny3 = R10*x3 + R11*y3 + R12*z3 + t1;
    const float nz3 = R20*x3 + R21*y3 + R22*z3 + t2;

    p[0] = make_float4(nx0, ny0, nz0, nx1);
    p[1] = make_float4(ny1, nz1, nx2, ny2);
    p[2] = make_float4(nz2, nx3, ny3, nz3);
}

extern "C" void kernel_launch(void* const* d_in, const int* in_sizes, int n_in,
                              void* d_out, int out_size, void* d_ws, size_t ws_size,
                              hipStream_t stream) {
    const float* net_in  = (const float*)d_in[0];
    const float* shift_p = (const float*)d_in[1];
    const float* a_p     = (const float*)d_in[2];
    const float* b_p     = (const float*)d_in[3];
    float* out = (float*)d_out;

    const int B = in_sizes[0] / (NPTS * NCH);   // 8192

    float* sums = (float*)d_ws;                 // B * 16 floats
    float* Rt   = sums + (size_t)B * 16;        // B * 12 floats

    reduce_kernel<<<B / BPB, BLK, 0, stream>>>(net_in, shift_p, a_p, b_p, sums, out);
    solve_kernel<<<(B + 63) / 64, 64, 0, stream>>>(sums, Rt, B);
    apply_kernel<<<(B * 50 + BLK - 1) / BLK, BLK, 0, stream>>>(Rt, out, B);
}

// Round 4
// 165.781 us; speedup vs baseline: 2.5202x; 1.0756x over previous
//
#include <hip/hip_runtime.h>
#include <math.h>

#define NPTS 200
#define NCH  13
#define BLK  256
#define FLT_PER_BATCH (NPTS * NCH)          // 2600
#define F4_PER_BATCH  (FLT_PER_BATCH / 4)   // 650

// ---------------------------------------------------------------------------
// Kernel 1: reduce — one wave per batch, wave-private LDS, ZERO barriers.
// Writes the 16 weighted sums per batch.
// ---------------------------------------------------------------------------
__global__ __launch_bounds__(BLK) void reduce_kernel(
    const float* __restrict__ net_in,   // (B, 200, 13)
    const float* __restrict__ shift_p,
    const float* __restrict__ a_p,
    const float* __restrict__ b_p,
    float* __restrict__ sums)           // (B, 16)
{
    __shared__ float s_in[4 * FLT_PER_BATCH];   // 4 waves * 2600 floats (41.6 KB)
    __shared__ float s_part[4][16][20];         // per-wave 16x16 transpose (5.1 KB)

    const int tid = threadIdx.x;
    const int w   = tid >> 6;                   // wave id = local batch
    const int l   = tid & 63;
    const int b   = blockIdx.x * 4 + w;         // global batch

    const float shift = shift_p[0];
    const float aa    = a_p[0];
    const float bb    = b_p[0];

    // ---- stage this wave's batch: 650 float4, 10-11 per lane, all in flight ----
    {
        const float4* src4 = (const float4*)(net_in + (size_t)b * FLT_PER_BATCH);
        float4* dst4 = (float4*)(s_in + w * FLT_PER_BATCH);
        #pragma unroll
        for (int j = 0; j < 10; ++j) dst4[l + 64 * j] = src4[l + 64 * j];
        if (l < 10) dst4[640 + l] = src4[640 + l];
    }
    // wave-synchronous: compiler inserts lgkmcnt/vmcnt waits; no __syncthreads.

    // ---- per-lane accumulation over 3-4 points ----
    float acc[16];
    #pragma unroll
    for (int k = 0; k < 16; ++k) acc[k] = 0.f;

    const float* base = s_in + w * FLT_PER_BATCH;
    #pragma unroll
    for (int j = 0; j < 4; ++j) {
        const int p = l + 64 * j;
        if (p < NPTS) {
            const float* q = base + p * NCH;    // stride 13: conflict-free
            float wt = aa * q[0] + bb;
            wt = fmaxf(wt, 0.f) + 1e-8f;
            float v1x = fmaf(shift, q[7],  q[1]);
            float v1y = fmaf(shift, q[8],  q[2]);
            float v1z = fmaf(shift, q[9],  q[3]);
            float v2x = fmaf(shift, q[10], q[4]);
            float v2y = fmaf(shift, q[11], q[5]);
            float v2z = fmaf(shift, q[12], q[6]);
            float wv2x = wt * v2x, wv2y = wt * v2y, wv2z = wt * v2z;
            acc[0] += wt;
            acc[1] += wt * v1x; acc[2] += wt * v1y; acc[3] += wt * v1z;
            acc[4] += wv2x;     acc[5] += wv2y;     acc[6] += wv2z;
            acc[7]  += wv2x * v1x; acc[8]  += wv2x * v1y; acc[9]  += wv2x * v1z;
            acc[10] += wv2y * v1x; acc[11] += wv2y * v1y; acc[12] += wv2y * v1z;
            acc[13] += wv2z * v1x; acc[14] += wv2z * v1y; acc[15] += wv2z * v1z;
        }
    }

    // ---- 2 shuffle levels: 64 -> 16 lanes ----
    #pragma unroll
    for (int k = 0; k < 16; ++k) {
        acc[k] += __shfl_down(acc[k], 32, 64);
        acc[k] += __shfl_down(acc[k], 16, 64);
    }

    // ---- 16x16 transpose in wave-private LDS (no barrier: same wave) ----
    if (l < 16) {
        float4* pp = (float4*)&s_part[w][l][0];
        pp[0] = make_float4(acc[0],  acc[1],  acc[2],  acc[3]);
        pp[1] = make_float4(acc[4],  acc[5],  acc[6],  acc[7]);
        pp[2] = make_float4(acc[8],  acc[9],  acc[10], acc[11]);
        pp[3] = make_float4(acc[12], acc[13], acc[14], acc[15]);
    }
    if (l < 16) {
        float s = 0.f;
        #pragma unroll
        for (int r = 0; r < 16; ++r) s += s_part[w][r][l];
        sums[(size_t)b * 16 + l] = s;          // 16-lane coalesced store
    }
}

// ---------------------------------------------------------------------------
// Kernel 2: one thread per batch — fp32 Horn quaternion / 4x4 Jacobi
// ---------------------------------------------------------------------------
__global__ __launch_bounds__(64) void solve_kernel(
    const float* __restrict__ sums,   // (B, 16)
    float* __restrict__ Rt,           // (B, 12)
    int B)
{
    const int b = blockIdx.x * 64 + threadIdx.x;
    if (b >= B) return;

    float f[16];
    #pragma unroll
    for (int k = 0; k < 16; ++k) f[k] = sums[(size_t)b * 16 + k];

    const float W = f[0];
    const float invW = 1.0f / W;
    float v1c[3] = { f[1] * invW, f[2] * invW, f[3] * invW };
    float v2c[3] = { f[4] * invW, f[5] * invW, f[6] * invW };

    float S[3][3];
    #pragma unroll
    for (int i = 0; i < 3; ++i)
        #pragma unroll
        for (int j = 0; j < 3; ++j)
            S[i][j] = f[7 + 3 * i + j] - W * v2c[i] * v1c[j];

    const float Sxx = S[0][0], Sxy = S[0][1], Sxz = S[0][2];
    const float Syx = S[1][0], Syy = S[1][1], Syz = S[1][2];
    const float Szx = S[2][0], Szy = S[2][1], Szz = S[2][2];

    float A[4][4];
    A[0][0] = Sxx + Syy + Szz;
    A[0][1] = Syz - Szy;  A[0][2] = Szx - Sxz;  A[0][3] = Sxy - Syx;
    A[1][1] = Sxx - Syy - Szz;
    A[1][2] = Sxy + Syx;  A[1][3] = Szx + Sxz;
    A[2][2] = -Sxx + Syy - Szz;
    A[2][3] = Syz + Szy;
    A[3][3] = -Sxx - Syy + Szz;
    A[1][0] = A[0][1]; A[2][0] = A[0][2]; A[3][0] = A[0][3];
    A[2][1] = A[1][2]; A[3][1] = A[1][3]; A[3][2] = A[2][3];

    float V[4][4] = {{1,0,0,0},{0,1,0,0},{0,0,1,0},{0,0,0,1}};

    const int prs[6][2] = {{0,1},{0,2},{0,3},{1,2},{1,3},{2,3}};
    for (int sweep = 0; sweep < 6; ++sweep) {
        #pragma unroll
        for (int r = 0; r < 6; ++r) {
            const int p = prs[r][0], q = prs[r][1];
            float apq = A[p][q];
            if (apq != 0.0f) {
                float tau = (A[q][q] - A[p][p]) / (2.0f * apq);
                float t = copysignf(1.0f, tau) /
                          (fabsf(tau) + sqrtf(1.0f + tau * tau));
                float c = rsqrtf(1.0f + t * t);
                float s = t * c;
                #pragma unroll
                for (int k = 0; k < 4; ++k) {
                    float a1 = A[p][k], a2 = A[q][k];
                    A[p][k] = c * a1 - s * a2;
                    A[q][k] = s * a1 + c * a2;
                }
                #pragma unroll
                for (int k = 0; k < 4; ++k) {
                    float a1 = A[k][p], a2 = A[k][q];
                    A[k][p] = c * a1 - s * a2;
                    A[k][q] = s * a1 + c * a2;
                }
                #pragma unroll
                for (int k = 0; k < 4; ++k) {
                    float a1 = V[k][p], a2 = V[k][q];
                    V[k][p] = c * a1 - s * a2;
                    V[k][q] = s * a1 + c * a2;
                }
            }
        }
    }

    int best = 0;
    #pragma unroll
    for (int i = 1; i < 4; ++i) if (A[i][i] > A[best][best]) best = i;
    const float q0 = V[0][best], qx = V[1][best], qy = V[2][best], qz = V[3][best];

    const float R00 = q0*q0 + qx*qx - qy*qy - qz*qz;
    const float R01 = 2.0f * (qx*qy - q0*qz);
    const float R02 = 2.0f * (qx*qz + q0*qy);
    const float R10 = 2.0f * (qx*qy + q0*qz);
    const float R11 = q0*q0 - qx*qx + qy*qy - qz*qz;
    const float R12 = 2.0f * (qy*qz - q0*qx);
    const float R20 = 2.0f * (qx*qz - q0*qy);
    const float R21 = 2.0f * (qy*qz + q0*qx);
    const float R22 = q0*q0 - qx*qx - qy*qy + qz*qz;

    const float t0 = v1c[0] - (R00 * v2c[0] + R01 * v2c[1] + R02 * v2c[2]);
    const float t1 = v1c[1] - (R10 * v2c[0] + R11 * v2c[1] + R12 * v2c[2]);
    const float t2 = v1c[2] - (R20 * v2c[0] + R21 * v2c[1] + R22 * v2c[2]);

    float* o = Rt + (size_t)b * 12;
    o[0] = R00; o[1]  = R01; o[2]  = R02;
    o[3] = R10; o[4]  = R11; o[5]  = R12;
    o[6] = R20; o[7]  = R21; o[8]  = R22;
    o[9] = t0;  o[10] = t1;  o[11] = t2;
}

// ---------------------------------------------------------------------------
// Kernel 3: apply — one thread per point, reads xyz2 straight from net_in
// (L3-hot after reduce), writes the (B,200,3) result. No LDS, no barriers.
// ---------------------------------------------------------------------------
__global__ __launch_bounds__(BLK) void apply_kernel(
    const float* __restrict__ net_in,   // (B, 200, 13)
    const float* __restrict__ Rt,       // (B, 12)
    float* __restrict__ out,            // (B, 200, 3)
    int total)                          // B * 200
{
    const int g = blockIdx.x * BLK + threadIdx.x;   // global point id
    if (g >= total) return;
    const int b = g / NPTS;
    const int p = g - b * NPTS;

    const float* q = net_in + (size_t)b * FLT_PER_BATCH + p * NCH;
    const float x = q[4], y = q[5], z = q[6];

    const float* r = Rt + (size_t)b * 12;           // wave-mostly-uniform: L1 hit
    const float ox = r[0] * x + r[1] * y + r[2] * z + r[9];
    const float oy = r[3] * x + r[4] * y + r[5] * z + r[10];
    const float oz = r[6] * x + r[7] * y + r[8] * z + r[11];

    float* o = out + (size_t)g * 3;
    o[0] = ox; o[1] = oy; o[2] = oz;
}

extern "C" void kernel_launch(void* const* d_in, const int* in_sizes, int n_in,
                              void* d_out, int out_size, void* d_ws, size_t ws_size,
                              hipStream_t stream) {
    const float* net_in  = (const float*)d_in[0];
    const float* shift_p = (const float*)d_in[1];
    const float* a_p     = (const float*)d_in[2];
    const float* b_p     = (const float*)d_in[3];
    float* out = (float*)d_out;

    const int B = in_sizes[0] / FLT_PER_BATCH;   // 8192

    float* sums = (float*)d_ws;                  // B * 16 floats
    float* Rt   = sums + (size_t)B * 16;         // B * 12 floats

    reduce_kernel<<<B / 4, BLK, 0, stream>>>(net_in, shift_p, a_p, b_p, sums);
    solve_kernel<<<(B + 63) / 64, 64, 0, stream>>>(sums, Rt, B);
    apply_kernel<<<(B * NPTS + BLK - 1) / BLK, BLK, 0, stream>>>(net_in, Rt, out, B * NPTS);
}